// Round 3
// baseline (312.856 us; speedup 1.0000x reference)
//
#include <hip/hip_runtime.h>
#include <hip/hip_bf16.h>
#include <stdint.h>

#define BATCH  8192
#define DIN    2048
#define DOUT   2048
#define NB     256
#define KSEL   26   // ceil(0.1*256)

typedef __attribute__((ext_vector_type(2))) float f32x2;
typedef __attribute__((ext_vector_type(4))) float f32x4;
typedef __attribute__((ext_vector_type(8))) __bf16 bf16x8;
typedef __attribute__((ext_vector_type(8))) unsigned short u16x8;
typedef __attribute__((ext_vector_type(4))) unsigned short u16x4;

__device__ __forceinline__ float bf2f(unsigned short u){
  union { unsigned int i; float f; } v; v.i = ((unsigned int)u) << 16; return v.f;
}
__device__ __forceinline__ unsigned short f2bf(float f){
  union { float f; unsigned int i; } v; v.f = f;
  unsigned int x = v.i;
  return (unsigned short)((x + 0x7FFFu + ((x >> 16) & 1u)) >> 16);  // RNE
}
// native cast path — compiler emits v_cvt_pk_bf16_f32 for pairs (RNE)
__device__ __forceinline__ unsigned short f2bf_c(float f){
  __bf16 b = (__bf16)f;
  union { __bf16 b; unsigned short u; } v; v.b = b; return v.u;
}

// ---------------- K0b: W -> W^T bf16 (wt[n][k] = W[k][n]) ----------------
__global__ __launch_bounds__(256) void conv_wt(const float* __restrict__ w, unsigned short* __restrict__ wt)
{
  __shared__ float tl[64][65];
  const int k0 = blockIdx.x * 64;
  const int n0 = blockIdx.y * 64;
  const int c  = threadIdx.x & 63;
  const int r4 = threadIdx.x >> 6;
  #pragma unroll
  for (int i = 0; i < 16; i++){
    const int r = r4 * 16 + i;
    tl[r][c] = w[(size_t)(k0 + r) * DOUT + n0 + c];
  }
  __syncthreads();
  #pragma unroll
  for (int i = 0; i < 16; i++){
    const int n = r4 * 16 + i;
    wt[(size_t)(n0 + n) * DIN + k0 + c] = f2bf(tl[c][n]);
  }
}

// ---------------- K1: gate GEMM, f32 (accuracy-critical for top-k) ----------
// Wave-uniform rows: each wave = 16 rows x 128 cols (2 cols/lane, 32 acc).
// x-row vector read per k = 4x ds_read_b128 broadcast (same addr all lanes,
// conflict-free); gw read straight from global (L2-resident, 2MB).
// Block = 4 waves = 32 rows x 256 cols; K-split 2 -> grid 512 (2 blocks/CU).
// FMA chain per output stays sequential k=0..1023 per split: gate values are
// bit-identical to the previously passing version. Also emits bf16 x.
__global__ __launch_bounds__(256) void gate_gemm(
    const float* __restrict__ x, const float* __restrict__ gw,
    float* __restrict__ part, unsigned short* __restrict__ xb)
{
  __shared__ float xT[32][36];    // [k][row], pad 36 (staging-write spread)
  const int b0   = blockIdx.x * 32;
  const int ks   = blockIdx.y;    // K-split 0/1
  const int t    = threadIdx.x;
  const int lane = t & 63;
  const int wv   = t >> 6;            // wave 0..3
  const int rg   = (wv >> 1) * 16;    // wave's row base within tile (0/16)
  const int cb   = (wv & 1) * 128 + (lane << 1);  // this lane's 2 cols

  float acc[16][2];
  #pragma unroll
  for (int i = 0; i < 16; i++){ acc[i][0] = 0.f; acc[i][1] = 0.f; }

  const int sr = t >> 3;          // x-stage row 0..31
  const int sk = (t & 7) * 4;     // x-stage k offset

  const int koff = ks * 1024;
  for (int kc = 0; kc < 1024; kc += 32){
    __syncthreads();              // protect xT from previous-iteration readers
    { // stage x transposed + emit bf16 x (each element exactly once grid-wide)
      const size_t gi = (size_t)(b0 + sr) * DIN + koff + kc + sk;
      f32x4 a = *(const f32x4*)&x[gi];
      u16x4 ob;
      #pragma unroll
      for (int j = 0; j < 4; j++) ob[j] = f2bf_c(a[j]);
      *(u16x4*)&xb[gi] = ob;
      #pragma unroll
      for (int j = 0; j < 4; j++) xT[sk + j][sr] = a[j];
    }
    __syncthreads();
    const float* gwp = &gw[(size_t)(koff + kc) * NB + cb];
    #pragma unroll 4
    for (int k = 0; k < 32; k++){
      f32x2 wvv = *(const f32x2*)(gwp + (size_t)k * NB);
      f32x4 xv0 = *(const f32x4*)&xT[k][rg];
      f32x4 xv1 = *(const f32x4*)&xT[k][rg + 4];
      f32x4 xv2 = *(const f32x4*)&xT[k][rg + 8];
      f32x4 xv3 = *(const f32x4*)&xT[k][rg + 12];
      #pragma unroll
      for (int j = 0; j < 4; j++){
        acc[j][0]      = fmaf(xv0[j], wvv[0], acc[j][0]);
        acc[j][1]      = fmaf(xv0[j], wvv[1], acc[j][1]);
        acc[j + 4][0]  = fmaf(xv1[j], wvv[0], acc[j + 4][0]);
        acc[j + 4][1]  = fmaf(xv1[j], wvv[1], acc[j + 4][1]);
        acc[j + 8][0]  = fmaf(xv2[j], wvv[0], acc[j + 8][0]);
        acc[j + 8][1]  = fmaf(xv2[j], wvv[1], acc[j + 8][1]);
        acc[j + 12][0] = fmaf(xv3[j], wvv[0], acc[j + 12][0]);
        acc[j + 12][1] = fmaf(xv3[j], wvv[1], acc[j + 12][1]);
      }
    }
  }
  float* dst = part + (size_t)ks * BATCH * NB;
  #pragma unroll
  for (int i = 0; i < 16; i++){
    const int row = b0 + rg + i;
    f32x2 o; o[0] = acc[i][0]; o[1] = acc[i][1];
    *(f32x2*)&dst[(size_t)row * NB + cb] = o;
  }
}

// ---------------- K2: reduce partials + bias, top-26 threshold, renormalize --
__global__ __launch_bounds__(256) void topk(float* __restrict__ part, const float* __restrict__ gb)
{
  const int lane = threadIdx.x & 63;
  const int row  = blockIdx.x * 4 + (threadIdx.x >> 6);
  f32x4* p0 = (f32x4*)&part[(size_t)row * NB];
  const f32x4* p1 = (const f32x4*)&part[(size_t)(BATCH + row) * NB];
  const f32x4* gbv = (const f32x4*)gb;
  f32x4 v = p0[lane] + p1[lane] + gbv[lane];

  const float NEG = -3.402823466e38f;
  float w0 = v[0], w1 = v[1], w2 = v[2], w3 = v[3];
  float thr = 0.f;
  for (int it = 0; it < KSEL; it++){
    float lm = fmaxf(fmaxf(w0, w1), fmaxf(w2, w3));
    float wm = lm;
    #pragma unroll
    for (int off = 32; off; off >>= 1) wm = fmaxf(wm, __shfl_xor(wm, off, 64));
    unsigned long long ball = __ballot(lm == wm);
    int first = __ffsll(ball) - 1;
    if (lane == first){
      if      (w0 == wm) w0 = NEG;
      else if (w1 == wm) w1 = NEG;
      else if (w2 == wm) w2 = NEG;
      else               w3 = NEG;
    }
    thr = wm;
  }
  float s = 0.f;
  #pragma unroll
  for (int j = 0; j < 4; j++) s += (v[j] >= thr) ? v[j] : 0.f;
  #pragma unroll
  for (int off = 32; off; off >>= 1) s += __shfl_xor(s, off, 64);
  const float d = s * (1.0f / NB);   // matches ref: res / (sum/n)
  f32x4 o;
  #pragma unroll
  for (int j = 0; j < 4; j++) o[j] = (v[j] >= thr) ? v[j] / d : 0.f;
  p0[lane] = o;                      // final gates overwrite partial 0
}

// ---------------- K3: gated main GEMM, bf16 MFMA 16x16x32 -------------------
// block: 128 rows x 128 cols (one output block q). 4 waves, each 64x64.
// gate folded into A during LDS staging (native bf16 casts -> cvt_pk). BK=64.
__global__ __launch_bounds__(256) void main_gemm(
    const unsigned short* __restrict__ xb,
    const unsigned short* __restrict__ wt,
    const float* __restrict__ g,
    const float* __restrict__ bias,
    float* __restrict__ out)
{
  __shared__ unsigned short xa[128][72];   // [row][k] gated bf16, +8 pad
  __shared__ unsigned short wb[128][72];   // [n][k]   bf16 (W^T), +8 pad
  __shared__ float gl[128 * 17];           // gates [row][p], stride 17

  const int q    = blockIdx.x;             // output block col 0..15
  const int b0   = blockIdx.y * 128;       // batch row tile
  const int t    = threadIdx.x;
  const int lane = t & 63;
  const int wid  = t >> 6;
  const int wr   = (wid >> 1) * 64;
  const int wc   = (wid & 1) * 64;
  const int l15  = lane & 15;
  const int l4   = lane >> 4;

  for (int e = t; e < 128 * 16; e += 256){
    const int r = e >> 4, p = e & 15;
    gl[r * 17 + p] = g[(size_t)(b0 + r) * NB + p * 16 + q];
  }

  f32x4 acc[4][4];
  #pragma unroll
  for (int m = 0; m < 4; m++)
    #pragma unroll
    for (int n = 0; n < 4; n++) acc[m][n] = (f32x4)0.0f;

  const int row_s = t >> 1;
  const int half  = t & 1;

  for (int kp = 0; kp < 32; kp++){         // 32 K-slices of 64 (p = kp>>1)
    const int p = kp >> 1;
    __syncthreads();                        // protect LDS reuse (covers gl on kp=0)
    { // stage gated A: xb * gate -> bf16 (lshl + mul + cvt_pk)
      const float gate = gl[row_s * 17 + p];
      const unsigned short* src = &xb[(size_t)(b0 + row_s) * DIN + kp * 64 + half * 32];
      unsigned short* dst = &xa[row_s][half * 32];
      #pragma unroll
      for (int c = 0; c < 4; c++){
        u16x8 u = *(const u16x8*)(src + c * 8);
        u16x8 o;
        #pragma unroll
        for (int j = 0; j < 8; j++) o[j] = f2bf_c(bf2f(u[j]) * gate);
        *(u16x8*)(dst + c * 8) = o;
      }
    }
    { // stage B: W^T tile copy
      const unsigned short* src = &wt[(size_t)(q * 128 + row_s) * DIN + kp * 64 + half * 32];
      unsigned short* dst = &wb[row_s][half * 32];
      #pragma unroll
      for (int c = 0; c < 4; c++)
        *(u16x8*)(dst + c * 8) = *(const u16x8*)(src + c * 8);
    }
    __syncthreads();
    #pragma unroll
    for (int ksi = 0; ksi < 2; ksi++){
      const int kk = ksi * 32 + l4 * 8;
      bf16x8 a[4], b[4];
      #pragma unroll
      for (int m = 0; m < 4; m++)
        a[m] = *(const bf16x8*)&xa[wr + m * 16 + l15][kk];
      #pragma unroll
      for (int n = 0; n < 4; n++)
        b[n] = *(const bf16x8*)&wb[wc + n * 16 + l15][kk];
      #pragma unroll
      for (int m = 0; m < 4; m++)
        #pragma unroll
        for (int n = 0; n < 4; n++)
          acc[m][n] = __builtin_amdgcn_mfma_f32_16x16x32_bf16(a[m], b[n], acc[m][n], 0, 0, 0);
    }
  }

  #pragma unroll
  for (int n = 0; n < 4; n++){
    const int col = q * 128 + wc + n * 16 + l15;
    const float bv = bias[col];
    #pragma unroll
    for (int m = 0; m < 4; m++){
      #pragma unroll
      for (int r = 0; r < 4; r++){
        const int row = b0 + wr + m * 16 + l4 * 4 + r;   // C/D: row=(lane>>4)*4+reg
        out[(size_t)row * DOUT + col] = acc[m][n][r] + bv;
      }
    }
  }
}

// ---------------- launch -----------------------------------------------------
extern "C" void kernel_launch(void* const* d_in, const int* in_sizes, int n_in,
                              void* d_out, int out_size, void* d_ws, size_t ws_size,
                              hipStream_t stream)
{
  const float* x    = (const float*)d_in[0];
  const float* w    = (const float*)d_in[1];
  const float* bias = (const float*)d_in[2];
  const float* gw   = (const float*)d_in[3];
  const float* gb   = (const float*)d_in[4];
  float* out = (float*)d_out;

  // ws layout: [0,16MB) gate partials (partial 0 becomes final gates),
  //            [16MB,24MB) W^T bf16, [24MB,56MB) x bf16
  float*          part = (float*)d_ws;
  unsigned short* wtb  = (unsigned short*)((char*)d_ws + (size_t)16 * 1024 * 1024);
  unsigned short* xbb  = (unsigned short*)((char*)d_ws + (size_t)24 * 1024 * 1024);

  conv_wt  <<<dim3(DIN / 64, DOUT / 64), 256, 0, stream>>>(w, wtb);
  gate_gemm<<<dim3(BATCH / 32, 2), 256, 0, stream>>>(x, gw, part, xbb);
  topk     <<<BATCH / 4, 256, 0, stream>>>(part, gb);
  main_gemm<<<dim3(16, BATCH / 128), 256, 0, stream>>>(xbb, wtb, part, bias, out);
}